// Round 8
// baseline (291.658 us; speedup 1.0000x reference)
//
#include <hip/hip_runtime.h>
#include <math.h>

// ---------------------------------------------------------------------------
// VQVAEZMultiScale round 12 — revert to best-measured composition.
//   Round-11 failed correctness: 2-pass match error (2<a1,c>, sigma~1.1e-3,
//   3x my estimate) blew through EPS_V=5e-3 over 75776x512 trials; a safe
//   gate flags 5-26% of rows -> rescue L2 traffic 60-300us. 2-pass is dead:
//   the referee pattern only works at tiny flag rates.
//   Also: round-9's B1-in-registers was a regression vs round-7's all-LDS
//   match (73-76 vs 69.0us) — per-lane dwordx4 gathers cost more than
//   wave-wide glds16, and occupancy was proven not to be the limiter.
//   This round = round-7 match_bulk (best measured, 69.0us) + round-10
//   prep/encode/fuse splits (the 281us run) + 3-pass EPS values.
// Workspace layout (float units), total ~57.7 MB (unchanged):
//   feat   [43008][256] f32        @ 0
//   partials [75776][8] float4     @ 11010048
//   prob   f32[43008]              @ 13434880
//   idx1   int[43008]              @ 13477888
//   idx2   int[32768]              @ 13520896
//   cnf    f32[1024]               @ 13553664
//   cnd    double[1024]            @ 13554688
//   cbs    bf16 tiled [book][split][codeblk][kc][128][32] @ 13556736
//   img1   [8][3][128][128]        @ 13818880
//   img2   [8][3][64][64]          @ 14212096
//   rlist  int[75776]              @ 14310400
//   dlist  int[32768]              @ 14386176
//   cnt    int[2]                  @ 14418944
// d_out scratch reuse (before fuse1): bf16 feat planes
//   [split][336 rowblk][8 kc][128][32] ushort, 22,020,096 ushorts = 44 MB.
// Output: out0 @0, zidx @8388608 (as float), ste0 @8454144 (all f32, NCHW)
// ---------------------------------------------------------------------------

#define FEAT_OFF   0
#define PART_OFF   11010048
#define PROB_OFF   13434880
#define IDX1_OFF   13477888
#define IDX2_OFF   13520896
#define CNF_OFF    13553664
#define CND_OFF    13554688
#define CBS_OFF    13556736
#define IMG1_OFF   13818880
#define IMG2_OFF   14212096
#define RLIST_OFF  14310400
#define DLIST_OFF  14386176
#define CNT_OFF    14418944

#define PLANE_STRIDE 11010048   // ushorts per split plane (336*8*128*32)

#define EPS_V 1e-3f          // 3-pass v abs error <= ~3e-5 -> 30x margin
#define EPS_P_REL 2e-3f      // prob rel error <= ~1e-4 -> 20x margin

typedef __attribute__((ext_vector_type(8))) short short8;
typedef __attribute__((ext_vector_type(4))) float f32x4;

__device__ inline unsigned short f2bf(float x) {
    unsigned u = __float_as_uint(x);
    return (unsigned short)((u + 0x7FFFu + ((u >> 16) & 1u)) >> 16);
}
__device__ inline float bf2f(unsigned short h) {
    return __uint_as_float(((unsigned)h) << 16);
}
// row-dependent channel-quad swizzle: 2-way max bank aliasing on b128 reads
__device__ inline int rswz(int row) { return (row & 3) ^ ((row >> 2) & 3); }

// global -> LDS direct copy, 16 B per lane. LDS dest must be wave-uniform.
__device__ inline void glds16(const unsigned short* g, unsigned short* l) {
    __builtin_amdgcn_global_load_lds(
        (const __attribute__((address_space(1))) void*)g,
        (__attribute__((address_space(3))) void*)l, 16, 0, 0);
}

// ---- fused prep: zero_cnt + bilinear ds (2 scales) + code norms + cb split
__launch_bounds__(256)
__global__ void prep(const float* __restrict__ image,
                     const float* __restrict__ codebooks,
                     float* __restrict__ img1, float* __restrict__ img2,
                     double* __restrict__ cnd, float* __restrict__ cnf,
                     unsigned short* __restrict__ cbs, int* __restrict__ cnt) {
    int bid = blockIdx.x, tid = threadIdx.x;
    if (bid == 0 && tid < 2) cnt[tid] = 0;
    if (bid < 1536) {                       // ds scale 1: 128x128, o=0, f=2
        int i = bid * 256 + tid;            // 8*3*128*128 = 393216 exact
        int x = i & 127;
        int t = i >> 7;
        int y = t & 127;
        int bc = t >> 7;
        const float* base = image + ((size_t)bc * 256 + (size_t)(y * 2)) * 256;
        int cx = x * 2;
        float v00 = base[cx],     v10 = base[256 + cx];
        float v01 = base[cx + 1], v11 = base[256 + cx + 1];
        img1[i] = ((v00 + v10) * 0.5f + (v01 + v11) * 0.5f) * 0.5f;
    } else if (bid < 1920) {                // ds scale 2: 64x64, o=1, f=4
        int i = (bid - 1536) * 256 + tid;   // 8*3*64*64 = 98304 exact
        int x = i & 63;
        int t = i >> 6;
        int y = t & 63;
        int bc = t >> 6;
        const float* base = image + ((size_t)bc * 256 + (size_t)(y * 4 + 1)) * 256;
        int cx = x * 4 + 1;
        float v00 = base[cx],     v10 = base[256 + cx];
        float v01 = base[cx + 1], v11 = base[256 + cx + 1];
        img2[i] = ((v00 + v10) * 0.5f + (v01 + v11) * 0.5f) * 0.5f;
    } else if (bid < 2176) {                // code norms: 4 rows/block, 1 wave/row
        int row = (bid - 1920) * 4 + (tid >> 6);
        int lane = tid & 63;
        const float* p = codebooks + (size_t)row * 256;
        double s = 0.0;
        for (int c = lane; c < 256; c += 64) {
            double v = (double)p[c];
            s = fma(v, v, s);
        }
        #pragma unroll
        for (int off = 32; off; off >>= 1) s += __shfl_down(s, off);
        if (lane == 0) { cnd[row] = s; cnf[row] = (float)s; }
    } else {                                // split_cb: tiled+swizzled bf16 planes
        int i = (bid - 2176) * 256 + tid;   // 2*512*256 = 262144 exact
        int book = i >> 17, rem = i & 131071;
        int code = rem >> 8, ch = rem & 255;
        float c = codebooks[(size_t)book * 131072 + rem];
        unsigned short h0 = f2bf(c);
        unsigned short h1 = f2bf(c - bf2f(h0));
        int codeblk = code >> 7, row = code & 127;
        int kc = ch >> 5, q = (ch >> 3) & 3, j = ch & 7;
        int qs = q ^ rswz(row);
        size_t off = ((((size_t)(book * 2) * 4 + codeblk) * 8 + kc) * 128 + row) * 32 + qs * 8 + j;
        cbs[off] = h0;                      // split 0
        cbs[off + 4 * 32768] = h1;          // split 1
    }
}

// ---- stride-4 patchify conv, all 3 scales; scale-0 rows split into x-halves.
//      featbf (hi+lo planes) flushed every 4 positions by all 256 threads.
__launch_bounds__(256)
__global__ void encode_all(const float* __restrict__ image,
                           const float* __restrict__ img1,
                           const float* __restrict__ img2,
                           const float* __restrict__ w,
                           const float* __restrict__ bias,
                           float* __restrict__ feat,
                           unsigned short* __restrict__ featbf) {
    __shared__ float patch[12 * 128];                       // <=128 cols per block
    __shared__ __align__(16) unsigned short pk[2][4][2][256];  // [buf][pos][plane][ch]
    int bid = blockIdx.x;
    const float* img; int Hout, rowbase, local, xbase, npos, Wimg, WL, colbase;
    if (bid < 1024) {        // scale 0: 512 rows x 2 x-halves
        img = image; Hout = 64; rowbase = 0;
        local = bid >> 1; int half = bid & 1;
        xbase = half * 32; npos = 32; Wimg = 256; WL = 128; colbase = half * 128;
    } else if (bid < 1280) { // scale 1: 256 rows
        img = img1; Hout = 32; rowbase = 32768;
        local = bid - 1024; xbase = 0; npos = 32; Wimg = 128; WL = 128; colbase = 0;
    } else {                 // scale 2: 128 rows
        img = img2; Hout = 16; rowbase = 40960;
        local = bid - 1280; xbase = 0; npos = 16; Wimg = 64; WL = 64; colbase = 0;
    }
    int Wout = Hout;
    int tid = threadIdx.x;
    int b = local / Hout, y = local % Hout;
    int Himg = Hout * 4;

    const float* ibase = img + (size_t)b * 3 * Himg * Wimg;
    int nload = 12 * WL;
    for (int i = tid; i < nload; i += 256) {
        int cl = i % WL, r = i / WL;         // r = ci*4 + kh
        int ci = r >> 2, kh = r & 3;
        patch[r * WL + cl] = ibase[((size_t)ci * Himg + 4 * y + kh) * Wimg + colbase + cl];
    }
    float wr[48];
    #pragma unroll
    for (int j = 0; j < 48; j++) wr[j] = w[tid * 48 + j];
    float bv = bias[tid];
    __syncthreads();

    // flush mapping: 256 threads = 4 pos x 2 planes x 8 kc x 4 quad-groups
    int fp = tid >> 6, fwp = (tid >> 5) & 1, fkc = (tid >> 2) & 7, fwg = tid & 3;
    int rb = rowbase + (b * Hout + y) * Wout + xbase;
    for (int x0 = 0; x0 < npos; x0 += 4) {
        int buf = (x0 >> 2) & 1;
        #pragma unroll
        for (int p = 0; p < 4; p++) {
            int xl = x0 + p;                 // local position; patch col = 4*xl
            float acc = 0.f;
            #pragma unroll
            for (int ci = 0; ci < 3; ci++)
                #pragma unroll
                for (int kh = 0; kh < 4; kh++) {
                    const float* pr = &patch[(ci * 4 + kh) * WL + 4 * xl];
                    #pragma unroll
                    for (int kw = 0; kw < 4; kw++)
                        acc = fmaf(pr[kw], wr[ci * 16 + kh * 4 + kw], acc);
                }
            float val = acc + bv;
            feat[(size_t)(rb + xl) * 256 + tid] = val;
            unsigned short hi = f2bf(val);
            pk[buf][p][0][tid] = hi;
            pk[buf][p][1][tid] = f2bf(val - bf2f(hi));
        }
        __syncthreads();                   // dbuf: one barrier per 4 positions
        {
            int r = rb + x0 + fp;
            int rowblk = r >> 7, rrow = r & 127;
            int ch0 = fkc * 32 + ((fwg ^ rswz(rrow)) << 3);
            uint4 v = *(const uint4*)&pk[buf][fp][fwp][ch0];
            size_t off = (((size_t)rowblk * 8 + fkc) * 128 + rrow) * 32 + fwg * 8
                       + (size_t)fwp * PLANE_STRIDE;
            *(uint4*)&featbf[off] = v;
        }
    }
}

// ---- bulk MFMA match (round-7 structure: best measured, 69.0us).
//      Block: 128 virtual-rows x 128 codes; grid 592x4. All operands via
//      glds16 double-buffer (64 KB LDS); counted vmcnt(8) depth-2 pipeline.
__launch_bounds__(256, 2)
__global__ void match_bulk(const unsigned short* __restrict__ featbf,
                           const unsigned short* __restrict__ cbs,
                           const float* __restrict__ cnf,
                           float* __restrict__ partials) {
    __shared__ unsigned short A0s[2][4096], A1s[2][4096], B0s[2][4096], B1s[2][4096];
    // bijective XCD swizzle: 2368 = 8*296; co-locate the 4 codeblk blocks of a
    // rowtile on one XCD L2 so the feat tile is fetched once, not 4x.
    int bid0 = blockIdx.x;
    int bid = (bid0 & 7) * 296 + (bid0 >> 3);
    int codeblk = bid & 3, rowtile = bid >> 2;     // 4 x 592
    int book = (rowtile >= 336) ? 1 : 0;
    int rowblk = book ? rowtile - 336 : rowtile;
    int vr0 = rowtile * 128;
    int tid = threadIdx.x;
    int wid = tid >> 6, l = tid & 63;
    int waveY = wid & 1, waveX = wid >> 1;
    int lm = l & 15, lq = l >> 4;
    int slot = lq ^ rswz(lm);                      // lane-constant swizzled quad
    int wlds = wid * 512;                          // ushort units, 1 KiB chunks

    // acc[ct][rt]: row (lq*4+j) = code within ct-tile, col (lm) = feat row
    f32x4 acc[4][4];
    #pragma unroll
    for (int ct = 0; ct < 4; ct++)
        #pragma unroll
        for (int rt = 0; rt < 4; rt++) acc[ct][rt] = (f32x4)0.0f;

    const unsigned short* gA0 = featbf + (size_t)rowblk * 32768 + tid * 8;
    const unsigned short* gA1 = gA0 + PLANE_STRIDE;
    const unsigned short* gB0 = cbs + ((size_t)(book * 8) + codeblk) * 32768 + tid * 8;
    const unsigned short* gB1 = gB0 + 4 * 32768;

    auto STAGE = [&](int buf, int kc) {            // 8 glds16 = 8 vmcnt units
        const unsigned short* ga0 = gA0 + kc * 4096;
        const unsigned short* ga1 = gA1 + kc * 4096;
        const unsigned short* gb0 = gB0 + kc * 4096;
        const unsigned short* gb1 = gB1 + kc * 4096;
        #pragma unroll
        for (int i = 0; i < 2; i++) {
            glds16(ga0 + i * 2048, &A0s[buf][i * 2048 + wlds]);
            glds16(ga1 + i * 2048, &A1s[buf][i * 2048 + wlds]);
            glds16(gb0 + i * 2048, &B0s[buf][i * 2048 + wlds]);
            glds16(gb1 + i * 2048, &B1s[buf][i * 2048 + wlds]);
        }
    };

    short8 a0[4], a1[4], b0[4], b1[4];
    auto LOADFRAG = [&](int cur) {                 // 16 ds_read_b128
        #pragma unroll
        for (int t = 0; t < 4; t++) {
            int ra = (waveY * 64 + t * 16 + lm) * 32 + slot * 8;
            int rbx = (waveX * 64 + t * 16 + lm) * 32 + slot * 8;
            a0[t] = *(const short8*)&A0s[cur][ra];
            a1[t] = *(const short8*)&A1s[cur][ra];
            b0[t] = *(const short8*)&B0s[cur][rbx];
            b1[t] = *(const short8*)&B1s[cur][rbx];
        }
    };
    auto DOMFMA = [&]() {
        __builtin_amdgcn_s_setprio(1);
        #pragma unroll
        for (int ct = 0; ct < 4; ct++)
            #pragma unroll
            for (int rt = 0; rt < 4; rt++) {
                acc[ct][rt] = __builtin_amdgcn_mfma_f32_16x16x32_bf16(b0[ct], a0[rt], acc[ct][rt], 0, 0, 0);
                acc[ct][rt] = __builtin_amdgcn_mfma_f32_16x16x32_bf16(b1[ct], a0[rt], acc[ct][rt], 0, 0, 0);
                acc[ct][rt] = __builtin_amdgcn_mfma_f32_16x16x32_bf16(b0[ct], a1[rt], acc[ct][rt], 0, 0, 0);
            }
        __builtin_amdgcn_s_setprio(0);
    };

    // prologue: tiles 0 and 1 fully issued (16 outstanding)
    STAGE(0, 0);
    STAGE(1, 1);

    // steady state: wait vmcnt(8) = tile kc landed (tile kc+1 still in flight)
#define MB_STEP(KC)                                                        \
    do {                                                                   \
        asm volatile("s_waitcnt vmcnt(8)" ::: "memory");                   \
        __builtin_amdgcn_s_barrier();                                      \
        __builtin_amdgcn_sched_barrier(0);                                 \
        LOADFRAG((KC) & 1);                                                \
        asm volatile("s_waitcnt lgkmcnt(0)" ::: "memory");                 \
        __builtin_amdgcn_sched_barrier(0);                                 \
        __builtin_amdgcn_s_barrier();                                      \
        __builtin_amdgcn_sched_barrier(0);                                 \
        STAGE((KC) & 1, (KC) + 2);                                         \
        DOMFMA();                                                          \
    } while (0)

    MB_STEP(0); MB_STEP(1); MB_STEP(2); MB_STEP(3); MB_STEP(4); MB_STEP(5);
#undef MB_STEP

    // kc = 6: tile 7's 8 loads still in flight; no further staging
    asm volatile("s_waitcnt vmcnt(8)" ::: "memory");
    __builtin_amdgcn_s_barrier();
    __builtin_amdgcn_sched_barrier(0);
    LOADFRAG(0);
    asm volatile("s_waitcnt lgkmcnt(0)" ::: "memory");
    __builtin_amdgcn_sched_barrier(0);
    DOMFMA();
    // kc = 7: drain
    asm volatile("s_waitcnt vmcnt(0)" ::: "memory");
    __builtin_amdgcn_s_barrier();
    __builtin_amdgcn_sched_barrier(0);
    LOADFRAG(1);
    asm volatile("s_waitcnt lgkmcnt(0)" ::: "memory");
    __builtin_amdgcn_sched_barrier(0);
    DOMFMA();

    // per-thread codes: kbase + ct*16 + j, all 16 in-register
    int kbase = codeblk * 128 + waveX * 64 + lq * 4;
    float4 cnv4[4];
    #pragma unroll
    for (int ct = 0; ct < 4; ct++)
        cnv4[ct] = *(const float4*)&cnf[book * 512 + kbase + ct * 16];
    float4* part4 = (float4*)partials;

    #pragma unroll
    for (int rt = 0; rt < 4; rt++) {
        float v[4][4];
        #pragma unroll
        for (int ct = 0; ct < 4; ct++) {
            v[ct][0] = 2.0f * acc[ct][rt][0] - cnv4[ct].x;
            v[ct][1] = 2.0f * acc[ct][rt][1] - cnv4[ct].y;
            v[ct][2] = 2.0f * acc[ct][rt][2] - cnv4[ct].z;
            v[ct][3] = 2.0f * acc[ct][rt][3] - cnv4[ct].w;
        }
        // in-thread argmax over 16 codes (ascending index: strict > keeps first)
        float m1 = v[0][0], m2 = -3.4e38f;
        int k1 = kbase;
        #pragma unroll
        for (int ct = 0; ct < 4; ct++)
            #pragma unroll
            for (int j = 0; j < 4; j++) {
                if (ct == 0 && j == 0) continue;
                float val = v[ct][j];
                if (val > m1) { m2 = m1; m1 = val; k1 = kbase + ct * 16 + j; }
                else m2 = fmaxf(m2, val);
            }
        // cross-lane over lq (lanes 16 apart): 2 butterfly steps
        #pragma unroll
        for (int off = 16; off < 64; off <<= 1) {
            float mo1 = __shfl_xor(m1, off);
            float mo2 = __shfl_xor(m2, off);
            int ko1 = __shfl_xor(k1, off);
            if (mo1 > m1 || (mo1 == m1 && ko1 < k1)) { m2 = fmaxf(m1, mo2); m1 = mo1; k1 = ko1; }
            else m2 = fmaxf(m2, mo1);
        }
        float s = 0.f;
        if (!book) {                                // prob never consumed for book 1
            #pragma unroll
            for (int ct = 0; ct < 4; ct++)
                #pragma unroll
                for (int j = 0; j < 4; j++) s += __expf(v[ct][j] - m1);
            #pragma unroll
            for (int off = 16; off < 64; off <<= 1) s += __shfl_xor(s, off);
        }
        if (lq == 0) {
            int vr = vr0 + waveY * 64 + rt * 16 + lm;
            float4 st = make_float4(m1, m2, __int_as_float(k1), s);
            part4[(size_t)vr * 8 + codeblk * 2 + waveX] = st;
        }
    }
}

// ---- combine the 8 per-slice partials of each row; write idx/prob; flag rescues
__global__ void combine_rows(const float* __restrict__ partials,
                             int* __restrict__ idx1, int* __restrict__ idx2,
                             float* __restrict__ prob,
                             int* __restrict__ rlist, int* __restrict__ cnt) {
    int vr = blockIdx.x * 256 + threadIdx.x;      // grid 296*256 = 75776 exact
    const float4* p = (const float4*)partials + (size_t)vr * 8;
    float sm[8], ss[8];
    float4 a = p[0];
    float m1 = a.x, m2 = a.y; int k1 = __float_as_int(a.z);
    sm[0] = a.x; ss[0] = a.w;
    #pragma unroll
    for (int j = 1; j < 8; j++) {
        float4 b = p[j];
        sm[j] = b.x; ss[j] = b.w;
        int kk = __float_as_int(b.z);
        if (b.x > m1 || (b.x == m1 && kk < k1)) { m2 = fmaxf(m1, b.y); m1 = b.x; k1 = kk; }
        else m2 = fmaxf(m2, b.x);
    }
    float S = 0.f;
    #pragma unroll
    for (int j = 0; j < 8; j++) S += ss[j] * __expf(sm[j] - m1);
    if (vr < 43008) { idx1[vr] = k1; prob[vr] = 1.0f / S; }
    else idx2[vr - 43008] = k1;
    if (m1 - m2 < EPS_V) { int pos = atomicAdd(cnt, 1); rlist[pos] = vr; }
}

// ---- exact fp64 recompute for flagged rows (idx + prob)
__launch_bounds__(256)
__global__ void rescue_exact(const float* __restrict__ feat,
                             const float* __restrict__ codebooks,
                             const double* __restrict__ cnd,
                             const int* __restrict__ rlist, const int* __restrict__ cnt,
                             int* __restrict__ idx1, int* __restrict__ idx2,
                             float* __restrict__ prob) {
    __shared__ double sfd[256];
    __shared__ double rv[4]; __shared__ int rk[4]; __shared__ double rs[4];
    __shared__ double gvmax; __shared__ int gkmax;
    int tid = threadIdx.x;
    int lane = tid & 63, wave = tid >> 6;
    int n = cnt[0];
    for (int e = blockIdx.x; e < n; e += gridDim.x) {
        int vr = rlist[e];
        int book = vr >= 43008;
        int fr = book ? vr - 43008 : vr;
        sfd[tid] = (double)feat[(size_t)fr * 256 + tid];
        __syncthreads();
        const float* cb = codebooks + (size_t)book * 131072;
        double vloc[2]; int kk[2];
        #pragma unroll
        for (int h = 0; h < 2; h++) {
            int k = h * 256 + tid;
            const float* cp = cb + (size_t)k * 256;
            double d0 = 0.0, d1 = 0.0, d2 = 0.0, d3 = 0.0;
            for (int c = 0; c < 256; c += 4) {
                float4 cv = *(const float4*)&cp[c];
                d0 = fma((double)cv.x, sfd[c],     d0);
                d1 = fma((double)cv.y, sfd[c + 1], d1);
                d2 = fma((double)cv.z, sfd[c + 2], d2);
                d3 = fma((double)cv.w, sfd[c + 3], d3);
            }
            double dot = (d0 + d1) + (d2 + d3);
            vloc[h] = 2.0 * dot - cnd[book * 512 + k];
            kk[h] = k;
        }
        double bv = vloc[0]; int bk = kk[0];
        if (vloc[1] > bv || (vloc[1] == bv && kk[1] < bk)) { bv = vloc[1]; bk = kk[1]; }
        #pragma unroll
        for (int off = 32; off; off >>= 1) {
            double vo = __shfl_xor(bv, off);
            int ko = __shfl_xor(bk, off);
            if (vo > bv || (vo == bv && ko < bk)) { bv = vo; bk = ko; }
        }
        if (lane == 0) { rv[wave] = bv; rk[wave] = bk; }
        __syncthreads();
        if (tid == 0) {
            double v0 = rv[0]; int K = rk[0];
            #pragma unroll
            for (int w = 1; w < 4; w++)
                if (rv[w] > v0 || (rv[w] == v0 && rk[w] < K)) { v0 = rv[w]; K = rk[w]; }
            gvmax = v0; gkmax = K;
        }
        __syncthreads();
        double vm = gvmax;
        double s = exp(vloc[0] - vm) + exp(vloc[1] - vm);
        #pragma unroll
        for (int off = 32; off; off >>= 1) s += __shfl_xor(s, off);
        if (lane == 0) rs[wave] = s;
        __syncthreads();
        if (tid == 0) {
            double S = ((rs[0] + rs[1]) + rs[2]) + rs[3];
            if (book) idx2[fr] = gkmax;
            else { idx1[vr] = gkmax; prob[vr] = (float)(1.0 / S); }
        }
        __syncthreads();
    }
}

// ---- fuse stage 1: decide per pixel; defer prob-fragile pixels to fuse2.
//      2 channel-half blocks per (b,y); outZ/dlist writes gated to half 0.
__launch_bounds__(256)
__global__ void fuse1(const float* __restrict__ feat,
                      const float* __restrict__ prob,
                      const int* __restrict__ idx1, const int* __restrict__ idx2,
                      const float* __restrict__ codebooks,
                      float* __restrict__ out0, float* __restrict__ outZ,
                      float* __restrict__ outS,
                      int* __restrict__ dlist, int* __restrict__ cnt) {
    __shared__ int rsel_s[64], i1_s[64], i2_s[64], defer_s[64];
    int tid = threadIdx.x;
    int bid = blockIdx.x;
    int chh = bid & 1;                       // channel half
    int rowid = bid >> 1;
    int b = rowid >> 6, y = rowid & 63;

    if (tid < 64) {
        int x = tid;
        int r0 = (b * 64 + y) * 64 + x;
        int r1 = 32768 + (b * 32 + (y >> 1)) * 32 + (x >> 1);
        int r2 = 40960 + (b * 16 + (y >> 2)) * 16 + (x >> 2);
        float p0 = prob[r0], p1 = prob[r1], p2 = prob[r2];
        int rsel = r0; float best = p0;          // strict > keeps first-max
        if (p1 > best) { best = p1; rsel = r1; }
        if (p2 > best) { best = p2; rsel = r2; }
        float second = (rsel == r0) ? fmaxf(p1, p2)
                     : (rsel == r1) ? fmaxf(p0, p2) : fmaxf(p0, p1);
        int defer = (best - second < EPS_P_REL * best) ? 1 : 0;
        defer_s[x] = defer;
        if (defer) {
            if (chh == 0) {                  // half 0 owns list append + outZ
                int pos = atomicAdd(cnt + 1, 1);
                dlist[pos] = (b << 12) | (y << 6) | x;
            }
            rsel_s[x] = r0; i1_s[x] = 0; i2_s[x] = 0;   // unused
        } else {
            int i1 = idx1[rsel], i2 = idx2[r0];
            rsel_s[x] = rsel; i1_s[x] = i1; i2_s[x] = i2;
            if (chh == 0) {
                size_t zb = (size_t)b * 8192 + (size_t)y * 64 + x;
                outZ[zb] = (float)i1;
                outZ[zb + 4096] = (float)i2;
            }
        }
    }
    __syncthreads();

    int x = tid & 63, cc = tid >> 6;
    int r0 = (b * 64 + y) * 64 + x;
    const float* e0p = feat + (size_t)r0 * 256;
    const float* e1p = feat + (size_t)rsel_s[x] * 256;
    const float* q1p = codebooks + (size_t)i1_s[x] * 256;
    const float* q2p = codebooks + (size_t)(512 + i2_s[x]) * 256;
    int defer = defer_s[x];
    for (int it = 0; it < 8; it++) {
        int c = chh * 128 + it * 16 + cc * 4;
        float4 e0 = *(const float4*)&e0p[c];
        size_t o = (((size_t)b * 256 + c) * 64 + y) * 64 + x;
        out0[o]         = e0.x;                    // out0 never depends on decisions
        out0[o + 4096]  = e0.y;
        out0[o + 8192]  = e0.z;
        out0[o + 12288] = e0.w;
        if (!defer) {
            float4 e1 = *(const float4*)&e1p[c];
            float4 q1 = *(const float4*)&q1p[c];
            float4 q2 = *(const float4*)&q2p[c];
            float ef, qf;
            ef = (e1.x + e0.x) * 0.5f; qf = (q1.x + q2.x) * 0.5f; outS[o]         = ef + (qf - ef);
            ef = (e1.y + e0.y) * 0.5f; qf = (q1.y + q2.y) * 0.5f; outS[o + 4096]  = ef + (qf - ef);
            ef = (e1.z + e0.z) * 0.5f; qf = (q1.z + q2.z) * 0.5f; outS[o + 8192]  = ef + (qf - ef);
            ef = (e1.w + e0.w) * 0.5f; qf = (q1.w + q2.w) * 0.5f; outS[o + 12288] = ef + (qf - ef);
        }
    }
}

// ---- fuse stage 2: deferred pixels, full fp64 (3 rows x 512 codes each)
__launch_bounds__(256)
__global__ void fuse2(const float* __restrict__ feat,
                      const float* __restrict__ codebooks,
                      const double* __restrict__ cnd,
                      const int* __restrict__ idx2,
                      const int* __restrict__ dlist, const int* __restrict__ cnt,
                      float* __restrict__ outZ, float* __restrict__ outS) {
    __shared__ double sfd[256];
    __shared__ double rv[4]; __shared__ int rk[4]; __shared__ double rs[4];
    __shared__ double gvmax;
    __shared__ double pRes[3]; __shared__ int kRes[3];
    __shared__ int selS, i2S;
    int tid = threadIdx.x;
    int lane = tid & 63, wave = tid >> 6;
    int n = cnt[1];
    for (int e = blockIdx.x; e < n; e += gridDim.x) {
        int px = dlist[e];
        int b = px >> 12, y = (px >> 6) & 63, x = px & 63;
        int r0 = (b * 64 + y) * 64 + x;
        int r1 = 32768 + (b * 32 + (y >> 1)) * 32 + (x >> 1);
        int r2 = 40960 + (b * 16 + (y >> 2)) * 16 + (x >> 2);
        int rows[3] = {r0, r1, r2};
        for (int s3 = 0; s3 < 3; s3++) {
            sfd[tid] = (double)feat[(size_t)rows[s3] * 256 + tid];
            __syncthreads();
            double vloc[2];
            #pragma unroll
            for (int h = 0; h < 2; h++) {
                int k = h * 256 + tid;
                const float* cp = codebooks + (size_t)k * 256;
                double d0 = 0.0, d1 = 0.0, d2 = 0.0, d3 = 0.0;
                for (int c = 0; c < 256; c += 4) {
                    float4 cv = *(const float4*)&cp[c];
                    d0 = fma((double)cv.x, sfd[c],     d0);
                    d1 = fma((double)cv.y, sfd[c + 1], d1);
                    d2 = fma((double)cv.z, sfd[c + 2], d2);
                    d3 = fma((double)cv.w, sfd[c + 3], d3);
                }
                double dot = (d0 + d1) + (d2 + d3);
                vloc[h] = 2.0 * dot - cnd[k];
            }
            double bv = vloc[0]; int bk = tid;
            if (vloc[1] > bv) { bv = vloc[1]; bk = tid + 256; }
            #pragma unroll
            for (int off = 32; off; off >>= 1) {
                double vo = __shfl_xor(bv, off);
                int ko = __shfl_xor(bk, off);
                if (vo > bv || (vo == bv && ko < bk)) { bv = vo; bk = ko; }
            }
            if (lane == 0) { rv[wave] = bv; rk[wave] = bk; }
            __syncthreads();
            if (tid == 0) {
                double v0 = rv[0]; int K = rk[0];
                #pragma unroll
                for (int w = 1; w < 4; w++)
                    if (rv[w] > v0 || (rv[w] == v0 && rk[w] < K)) { v0 = rv[w]; K = rk[w]; }
                gvmax = v0; kRes[s3] = K;
            }
            __syncthreads();
            double vm = gvmax;
            double s = exp(vloc[0] - vm) + exp(vloc[1] - vm);
            #pragma unroll
            for (int off = 32; off; off >>= 1) s += __shfl_xor(s, off);
            if (lane == 0) rs[wave] = s;
            __syncthreads();
            if (tid == 0) pRes[s3] = 1.0 / (((rs[0] + rs[1]) + rs[2]) + rs[3]);
            __syncthreads();
        }
        if (tid == 0) {
            int sel = 0; double best = pRes[0];
            if (pRes[1] > best) { best = pRes[1]; sel = 1; }
            if (pRes[2] > best) { best = pRes[2]; sel = 2; }
            selS = sel;
            int i2 = idx2[r0];
            i2S = i2;
            size_t zb = (size_t)b * 8192 + (size_t)y * 64 + x;
            outZ[zb] = (float)kRes[sel];
            outZ[zb + 4096] = (float)i2;
        }
        __syncthreads();
        int sel = selS;
        int c = tid;
        float e0 = feat[(size_t)r0 * 256 + c];
        float e1 = feat[(size_t)rows[sel] * 256 + c];
        float q1 = codebooks[(size_t)kRes[sel] * 256 + c];
        float q2 = codebooks[(size_t)(512 + i2S) * 256 + c];
        float ef = (e1 + e0) * 0.5f;
        float qf = (q1 + q2) * 0.5f;
        size_t o = (((size_t)b * 256 + c) * 64 + y) * 64 + x;
        outS[o] = ef + (qf - ef);
        __syncthreads();
    }
}

extern "C" void kernel_launch(void* const* d_in, const int* in_sizes, int n_in,
                              void* d_out, int out_size, void* d_ws, size_t ws_size,
                              hipStream_t stream) {
    (void)in_sizes; (void)n_in; (void)out_size; (void)ws_size;
    const float* image     = (const float*)d_in[0];   // [8,3,256,256]
    const float* conv_w    = (const float*)d_in[1];   // [256,3,4,4]
    const float* conv_b    = (const float*)d_in[2];   // [256]
    const float* codebooks = (const float*)d_in[3];   // [4,512,256]

    float*  ws    = (float*)d_ws;
    float*  feat  = ws + FEAT_OFF;
    float*  parts = ws + PART_OFF;
    float*  prob  = ws + PROB_OFF;
    int*    idx1  = (int*)(ws + IDX1_OFF);
    int*    idx2  = (int*)(ws + IDX2_OFF);
    float*  cnf   = ws + CNF_OFF;
    double* cnd   = (double*)(ws + CND_OFF);
    unsigned short* cbs = (unsigned short*)(ws + CBS_OFF);
    float*  img1  = ws + IMG1_OFF;
    float*  img2  = ws + IMG2_OFF;
    int*    rlist = (int*)(ws + RLIST_OFF);
    int*    dlist = (int*)(ws + DLIST_OFF);
    int*    cnt   = (int*)(ws + CNT_OFF);

    float* out  = (float*)d_out;
    float* out0 = out;
    float* outZ = out + 8388608;
    float* outS = out + 8454144;
    // d_out doubles as scratch for the bf16 feat planes until fuse1 runs;
    // fuse1/fuse2 rewrite every output byte afterwards.
    unsigned short* featbf = (unsigned short*)d_out;

    prep<<<3200, 256, 0, stream>>>(image, codebooks, img1, img2, cnd, cnf, cbs, cnt);
    encode_all<<<1408, 256, 0, stream>>>(image, img1, img2, conv_w, conv_b, feat, featbf);
    match_bulk<<<2368, 256, 0, stream>>>(featbf, cbs, cnf, parts);
    combine_rows<<<296, 256, 0, stream>>>(parts, idx1, idx2, prob, rlist, cnt);
    rescue_exact<<<1024, 256, 0, stream>>>(feat, codebooks, cnd, rlist, cnt, idx1, idx2, prob);
    fuse1<<<1024, 256, 0, stream>>>(feat, prob, idx1, idx2, codebooks, out0, outZ, outS, dlist, cnt);
    fuse2<<<512, 256, 0, stream>>>(feat, codebooks, cnd, idx2, dlist, cnt, outZ, outS);
}

// Round 9
// 277.900 us; speedup vs baseline: 1.0495x; 1.0495x over previous
//
#include <hip/hip_runtime.h>
#include <math.h>

// ---------------------------------------------------------------------------
// VQVAEZMultiScale round 13 — fuse-path restructure: outS = q_fused (1-ulp
// identity), out0 written by encode via LDS transpose, feat round-trip gone.
//   Round-12: match at its structural limit (~70us, LDS+MFMA both ~70% busy
//   at 2 blocks/CU). The ~220us "rest" hides in fuse1's 64-way row-gathers
//   (4 streams x 16B/lane) and the feat write/read round-trip.
//   Algebra: ste0 = e_f + (q_f - e_f) == q_f to 1 ulp (<=1e-7 << 7.8e-3
//   absmax) -> fuse1 needs NO feat reads. Then encode writes out0 (NCHW)
//   directly; scale-0 feat lives only as out0 (rescue/fuse2 referee reads
//   it strided for ~55 rare rows). featbf hi plane -> outS scratch region,
//   lo plane -> ws (freed feat region).
// Memory map:
//   ws floats: feat12 [10240][256] @ 0 (scales 1-2 rows 32768..43007)
//              featbf_lo (11,010,048 ushorts) @ 2621440
//              partials @ 11010048 | prob @ 13434880 | idx1 @ 13477888
//              idx2 @ 13520896 | cnf @ 13553664 | cnd @ 13554688
//              cbs @ 13556736 | img1 @ 13818880 | img2 @ 14212096
//              rlist @ 14310400 | dlist @ 14386176 | cnt @ 14418944
//   d_out: out0 @0 (written by encode, FINAL), outZ @8388608,
//          outS @8454144 — hosts featbf_hi (11,010,048 ushorts) during
//          encode->match, overwritten by fuse1/fuse2 afterwards.
// ---------------------------------------------------------------------------

#define FEAT12_OFF 0
#define FBLO_OFF   2621440
#define PART_OFF   11010048
#define PROB_OFF   13434880
#define IDX1_OFF   13477888
#define IDX2_OFF   13520896
#define CNF_OFF    13553664
#define CND_OFF    13554688
#define CBS_OFF    13556736
#define IMG1_OFF   13818880
#define IMG2_OFF   14212096
#define RLIST_OFF  14310400
#define DLIST_OFF  14386176
#define CNT_OFF    14418944

#define EPS_V 1e-3f          // 3-pass v abs error <= ~3e-5 -> 30x margin
#define EPS_P_REL 2e-3f      // prob rel error <= ~1e-4 -> 20x margin

typedef __attribute__((ext_vector_type(8))) short short8;
typedef __attribute__((ext_vector_type(4))) float f32x4;

__device__ inline unsigned short f2bf(float x) {
    unsigned u = __float_as_uint(x);
    return (unsigned short)((u + 0x7FFFu + ((u >> 16) & 1u)) >> 16);
}
__device__ inline float bf2f(unsigned short h) {
    return __uint_as_float(((unsigned)h) << 16);
}
// row-dependent channel-quad swizzle: 2-way max bank aliasing on b128 reads
__device__ inline int rswz(int row) { return (row & 3) ^ ((row >> 2) & 3); }

// global -> LDS direct copy, 16 B per lane. LDS dest must be wave-uniform.
__device__ inline void glds16(const unsigned short* g, unsigned short* l) {
    __builtin_amdgcn_global_load_lds(
        (const __attribute__((address_space(1))) void*)g,
        (__attribute__((address_space(3))) void*)l, 16, 0, 0);
}

// feat row element: scale-0 rows live in out0 (NCHW), scales 1-2 in feat12.
__device__ inline float feat_elem(const float* __restrict__ out0,
                                  const float* __restrict__ feat12,
                                  int fr, int c) {
    if (fr < 32768) {
        int b = fr >> 12, y = (fr >> 6) & 63, x = fr & 63;
        return out0[(((size_t)b * 256 + c) * 64 + y) * 64 + x];
    }
    return feat12[(size_t)(fr - 32768) * 256 + c];
}

// ---- fused prep: zero_cnt + bilinear ds (2 scales) + code norms + cb split
__launch_bounds__(256)
__global__ void prep(const float* __restrict__ image,
                     const float* __restrict__ codebooks,
                     float* __restrict__ img1, float* __restrict__ img2,
                     double* __restrict__ cnd, float* __restrict__ cnf,
                     unsigned short* __restrict__ cbs, int* __restrict__ cnt) {
    int bid = blockIdx.x, tid = threadIdx.x;
    if (bid == 0 && tid < 2) cnt[tid] = 0;
    if (bid < 1536) {                       // ds scale 1: 128x128, o=0, f=2
        int i = bid * 256 + tid;            // 8*3*128*128 = 393216 exact
        int x = i & 127;
        int t = i >> 7;
        int y = t & 127;
        int bc = t >> 7;
        const float* base = image + ((size_t)bc * 256 + (size_t)(y * 2)) * 256;
        int cx = x * 2;
        float v00 = base[cx],     v10 = base[256 + cx];
        float v01 = base[cx + 1], v11 = base[256 + cx + 1];
        img1[i] = ((v00 + v10) * 0.5f + (v01 + v11) * 0.5f) * 0.5f;
    } else if (bid < 1920) {                // ds scale 2: 64x64, o=1, f=4
        int i = (bid - 1536) * 256 + tid;   // 8*3*64*64 = 98304 exact
        int x = i & 63;
        int t = i >> 6;
        int y = t & 63;
        int bc = t >> 6;
        const float* base = image + ((size_t)bc * 256 + (size_t)(y * 4 + 1)) * 256;
        int cx = x * 4 + 1;
        float v00 = base[cx],     v10 = base[256 + cx];
        float v01 = base[cx + 1], v11 = base[256 + cx + 1];
        img2[i] = ((v00 + v10) * 0.5f + (v01 + v11) * 0.5f) * 0.5f;
    } else if (bid < 2176) {                // code norms: 4 rows/block, 1 wave/row
        int row = (bid - 1920) * 4 + (tid >> 6);
        int lane = tid & 63;
        const float* p = codebooks + (size_t)row * 256;
        double s = 0.0;
        for (int c = lane; c < 256; c += 64) {
            double v = (double)p[c];
            s = fma(v, v, s);
        }
        #pragma unroll
        for (int off = 32; off; off >>= 1) s += __shfl_down(s, off);
        if (lane == 0) { cnd[row] = s; cnf[row] = (float)s; }
    } else {                                // split_cb: tiled+swizzled bf16 planes
        int i = (bid - 2176) * 256 + tid;   // 2*512*256 = 262144 exact
        int book = i >> 17, rem = i & 131071;
        int code = rem >> 8, ch = rem & 255;
        float c = codebooks[(size_t)book * 131072 + rem];
        unsigned short h0 = f2bf(c);
        unsigned short h1 = f2bf(c - bf2f(h0));
        int codeblk = code >> 7, row = code & 127;
        int kc = ch >> 5, q = (ch >> 3) & 3, j = ch & 7;
        int qs = q ^ rswz(row);
        size_t off = ((((size_t)(book * 2) * 4 + codeblk) * 8 + kc) * 128 + row) * 32 + qs * 8 + j;
        cbs[off] = h0;                      // split 0
        cbs[off + 4 * 32768] = h1;          // split 1
    }
}

// ---- stride-4 patchify conv, all 3 scales; scale-0 rows split into x-halves.
//      Emits: featbf hi/lo planes (tiled+swizzled, separate buffers), out0
//      (NCHW, scale-0 only, via LDS transpose), feat12 (scales 1-2 rows).
__launch_bounds__(256)
__global__ void encode_all(const float* __restrict__ image,
                           const float* __restrict__ img1,
                           const float* __restrict__ img2,
                           const float* __restrict__ w,
                           const float* __restrict__ bias,
                           float* __restrict__ feat12,
                           unsigned short* __restrict__ fbh,
                           unsigned short* __restrict__ fbl,
                           float* __restrict__ out0) {
    __shared__ float patch[12 * 128];                          // <=128 cols
    __shared__ __align__(16) unsigned short pk[2][8][2][256];  // [buf][pos][plane][ch]
    __shared__ __align__(16) float vf[2][8][256];              // [buf][pos][ch]
    int bid = blockIdx.x;
    const float* img; int Hout, rowbase, local, xbase, npos, Wimg, WL, colbase;
    int isS0 = 0;
    if (bid < 1024) {        // scale 0: 512 rows x 2 x-halves
        img = image; Hout = 64; rowbase = 0; isS0 = 1;
        local = bid >> 1; int half = bid & 1;
        xbase = half * 32; npos = 32; Wimg = 256; WL = 128; colbase = half * 128;
    } else if (bid < 1280) { // scale 1: 256 rows
        img = img1; Hout = 32; rowbase = 32768;
        local = bid - 1024; xbase = 0; npos = 32; Wimg = 128; WL = 128; colbase = 0;
    } else {                 // scale 2: 128 rows
        img = img2; Hout = 16; rowbase = 40960;
        local = bid - 1280; xbase = 0; npos = 16; Wimg = 64; WL = 64; colbase = 0;
    }
    int Wout = Hout;
    int tid = threadIdx.x;
    int b = local / Hout, y = local % Hout;
    int Himg = Hout * 4;

    const float* ibase = img + (size_t)b * 3 * Himg * Wimg;
    int nload = 12 * WL;
    for (int i = tid; i < nload; i += 256) {
        int cl = i % WL, r = i / WL;         // r = ci*4 + kh
        int ci = r >> 2, kh = r & 3;
        patch[r * WL + cl] = ibase[((size_t)ci * Himg + 4 * y + kh) * Wimg + colbase + cl];
    }
    float wr[48];
    #pragma unroll
    for (int j = 0; j < 48; j++) wr[j] = w[tid * 48 + j];
    float bv = bias[tid];
    __syncthreads();

    int rb = rowbase + (b * Hout + y) * Wout + xbase;
    for (int x0 = 0; x0 < npos; x0 += 8) {
        int buf = (x0 >> 3) & 1;
        #pragma unroll
        for (int p = 0; p < 8; p++) {
            int xl = x0 + p;                 // local position; patch col = 4*xl
            float acc = 0.f;
            #pragma unroll
            for (int ci = 0; ci < 3; ci++)
                #pragma unroll
                for (int kh = 0; kh < 4; kh++) {
                    const float* pr = &patch[(ci * 4 + kh) * WL + 4 * xl];
                    #pragma unroll
                    for (int kw = 0; kw < 4; kw++)
                        acc = fmaf(pr[kw], wr[ci * 16 + kh * 4 + kw], acc);
                }
            float val = acc + bv;
            unsigned short hi = f2bf(val);
            pk[buf][p][0][tid] = hi;
            pk[buf][p][1][tid] = f2bf(val - bf2f(hi));
            vf[buf][p][tid] = val;
            if (!isS0) feat12[(size_t)(rb + xl - 32768) * 256 + tid] = val;
        }
        __syncthreads();                   // dbuf: one barrier per 8 positions
        // featbf flush: 8 pos x 2 planes x 8 kc x 4 quads = 512 chunks, 2/thread
        #pragma unroll
        for (int s = tid; s < 512; s += 256) {
            int fp = s >> 6; int rest = s & 63;
            int fwp = rest >> 5, fkc = (rest >> 2) & 7, fwg = rest & 3;
            int r = rb + x0 + fp;
            int rowblk = r >> 7, rrow = r & 127;
            int ch0 = fkc * 32 + ((fwg ^ rswz(rrow)) << 3);
            uint4 v = *(const uint4*)&pk[buf][fp][fwp][ch0];
            size_t off = (((size_t)rowblk * 8 + fkc) * 128 + rrow) * 32 + fwg * 8;
            if (fwp) *(uint4*)&fbl[off] = v;
            else     *(uint4*)&fbh[off] = v;
        }
        // out0 flush (scale-0): thread=channel, 8 consecutive x -> 2 float4
        if (isS0) {
            int c = tid;
            size_t o = (((size_t)b * 256 + c) * 64 + y) * 64 + (xbase + x0);
            float4 v0 = make_float4(vf[buf][0][c], vf[buf][1][c], vf[buf][2][c], vf[buf][3][c]);
            float4 v1 = make_float4(vf[buf][4][c], vf[buf][5][c], vf[buf][6][c], vf[buf][7][c]);
            *(float4*)&out0[o]     = v0;
            *(float4*)&out0[o + 4] = v1;
        }
    }
}

// ---- bulk MFMA match (round-7 structure, best measured ~70us).
//      Block: 128 virtual-rows x 128 codes; grid 592x4. All operands via
//      glds16 double-buffer (64 KB LDS); counted vmcnt(8) depth-2 pipeline.
//      A hi/lo planes now come from two base pointers (fbh in d_out scratch,
//      fbl in ws) — identical internal tiled layout.
__launch_bounds__(256, 2)
__global__ void match_bulk(const unsigned short* __restrict__ fbh,
                           const unsigned short* __restrict__ fbl,
                           const unsigned short* __restrict__ cbs,
                           const float* __restrict__ cnf,
                           float* __restrict__ partials) {
    __shared__ unsigned short A0s[2][4096], A1s[2][4096], B0s[2][4096], B1s[2][4096];
    // bijective XCD swizzle: 2368 = 8*296; co-locate the 4 codeblk blocks of a
    // rowtile on one XCD L2 so the feat tile is fetched once, not 4x.
    int bid0 = blockIdx.x;
    int bid = (bid0 & 7) * 296 + (bid0 >> 3);
    int codeblk = bid & 3, rowtile = bid >> 2;     // 4 x 592
    int book = (rowtile >= 336) ? 1 : 0;
    int rowblk = book ? rowtile - 336 : rowtile;
    int vr0 = rowtile * 128;
    int tid = threadIdx.x;
    int wid = tid >> 6, l = tid & 63;
    int waveY = wid & 1, waveX = wid >> 1;
    int lm = l & 15, lq = l >> 4;
    int slot = lq ^ rswz(lm);                      // lane-constant swizzled quad
    int wlds = wid * 512;                          // ushort units, 1 KiB chunks

    // acc[ct][rt]: row (lq*4+j) = code within ct-tile, col (lm) = feat row
    f32x4 acc[4][4];
    #pragma unroll
    for (int ct = 0; ct < 4; ct++)
        #pragma unroll
        for (int rt = 0; rt < 4; rt++) acc[ct][rt] = (f32x4)0.0f;

    const unsigned short* gA0 = fbh + (size_t)rowblk * 32768 + tid * 8;
    const unsigned short* gA1 = fbl + (size_t)rowblk * 32768 + tid * 8;
    const unsigned short* gB0 = cbs + ((size_t)(book * 8) + codeblk) * 32768 + tid * 8;
    const unsigned short* gB1 = gB0 + 4 * 32768;

    auto STAGE = [&](int buf, int kc) {            // 8 glds16 = 8 vmcnt units
        const unsigned short* ga0 = gA0 + kc * 4096;
        const unsigned short* ga1 = gA1 + kc * 4096;
        const unsigned short* gb0 = gB0 + kc * 4096;
        const unsigned short* gb1 = gB1 + kc * 4096;
        #pragma unroll
        for (int i = 0; i < 2; i++) {
            glds16(ga0 + i * 2048, &A0s[buf][i * 2048 + wlds]);
            glds16(ga1 + i * 2048, &A1s[buf][i * 2048 + wlds]);
            glds16(gb0 + i * 2048, &B0s[buf][i * 2048 + wlds]);
            glds16(gb1 + i * 2048, &B1s[buf][i * 2048 + wlds]);
        }
    };

    short8 a0[4], a1[4], b0[4], b1[4];
    auto LOADFRAG = [&](int cur) {                 // 16 ds_read_b128
        #pragma unroll
        for (int t = 0; t < 4; t++) {
            int ra = (waveY * 64 + t * 16 + lm) * 32 + slot * 8;
            int rbx = (waveX * 64 + t * 16 + lm) * 32 + slot * 8;
            a0[t] = *(const short8*)&A0s[cur][ra];
            a1[t] = *(const short8*)&A1s[cur][ra];
            b0[t] = *(const short8*)&B0s[cur][rbx];
            b1[t] = *(const short8*)&B1s[cur][rbx];
        }
    };
    auto DOMFMA = [&]() {
        __builtin_amdgcn_s_setprio(1);
        #pragma unroll
        for (int ct = 0; ct < 4; ct++)
            #pragma unroll
            for (int rt = 0; rt < 4; rt++) {
                acc[ct][rt] = __builtin_amdgcn_mfma_f32_16x16x32_bf16(b0[ct], a0[rt], acc[ct][rt], 0, 0, 0);
                acc[ct][rt] = __builtin_amdgcn_mfma_f32_16x16x32_bf16(b1[ct], a0[rt], acc[ct][rt], 0, 0, 0);
                acc[ct][rt] = __builtin_amdgcn_mfma_f32_16x16x32_bf16(b0[ct], a1[rt], acc[ct][rt], 0, 0, 0);
            }
        __builtin_amdgcn_s_setprio(0);
    };

    // prologue: tiles 0 and 1 fully issued (16 outstanding)
    STAGE(0, 0);
    STAGE(1, 1);

    // steady state: wait vmcnt(8) = tile kc landed (tile kc+1 still in flight)
#define MB_STEP(KC)                                                        \
    do {                                                                   \
        asm volatile("s_waitcnt vmcnt(8)" ::: "memory");                   \
        __builtin_amdgcn_s_barrier();                                      \
        __builtin_amdgcn_sched_barrier(0);                                 \
        LOADFRAG((KC) & 1);                                                \
        asm volatile("s_waitcnt lgkmcnt(0)" ::: "memory");                 \
        __builtin_amdgcn_sched_barrier(0);                                 \
        __builtin_amdgcn_s_barrier();                                      \
        __builtin_amdgcn_sched_barrier(0);                                 \
        STAGE((KC) & 1, (KC) + 2);                                         \
        DOMFMA();                                                          \
    } while (0)

    MB_STEP(0); MB_STEP(1); MB_STEP(2); MB_STEP(3); MB_STEP(4); MB_STEP(5);
#undef MB_STEP

    // kc = 6: tile 7's 8 loads still in flight; no further staging
    asm volatile("s_waitcnt vmcnt(8)" ::: "memory");
    __builtin_amdgcn_s_barrier();
    __builtin_amdgcn_sched_barrier(0);
    LOADFRAG(0);
    asm volatile("s_waitcnt lgkmcnt(0)" ::: "memory");
    __builtin_amdgcn_sched_barrier(0);
    DOMFMA();
    // kc = 7: drain
    asm volatile("s_waitcnt vmcnt(0)" ::: "memory");
    __builtin_amdgcn_s_barrier();
    __builtin_amdgcn_sched_barrier(0);
    LOADFRAG(1);
    asm volatile("s_waitcnt lgkmcnt(0)" ::: "memory");
    __builtin_amdgcn_sched_barrier(0);
    DOMFMA();

    // per-thread codes: kbase + ct*16 + j, all 16 in-register
    int kbase = codeblk * 128 + waveX * 64 + lq * 4;
    float4 cnv4[4];
    #pragma unroll
    for (int ct = 0; ct < 4; ct++)
        cnv4[ct] = *(const float4*)&cnf[book * 512 + kbase + ct * 16];
    float4* part4 = (float4*)partials;

    #pragma unroll
    for (int rt = 0; rt < 4; rt++) {
        float v[4][4];
        #pragma unroll
        for (int ct = 0; ct < 4; ct++) {
            v[ct][0] = 2.0f * acc[ct][rt][0] - cnv4[ct].x;
            v[ct][1] = 2.0f * acc[ct][rt][1] - cnv4[ct].y;
            v[ct][2] = 2.0f * acc[ct][rt][2] - cnv4[ct].z;
            v[ct][3] = 2.0f * acc[ct][rt][3] - cnv4[ct].w;
        }
        // in-thread argmax over 16 codes (ascending index: strict > keeps first)
        float m1 = v[0][0], m2 = -3.4e38f;
        int k1 = kbase;
        #pragma unroll
        for (int ct = 0; ct < 4; ct++)
            #pragma unroll
            for (int j = 0; j < 4; j++) {
                if (ct == 0 && j == 0) continue;
                float val = v[ct][j];
                if (val > m1) { m2 = m1; m1 = val; k1 = kbase + ct * 16 + j; }
                else m2 = fmaxf(m2, val);
            }
        // cross-lane over lq (lanes 16 apart): 2 butterfly steps
        #pragma unroll
        for (int off = 16; off < 64; off <<= 1) {
            float mo1 = __shfl_xor(m1, off);
            float mo2 = __shfl_xor(m2, off);
            int ko1 = __shfl_xor(k1, off);
            if (mo1 > m1 || (mo1 == m1 && ko1 < k1)) { m2 = fmaxf(m1, mo2); m1 = mo1; k1 = ko1; }
            else m2 = fmaxf(m2, mo1);
        }
        float s = 0.f;
        if (!book) {                                // prob never consumed for book 1
            #pragma unroll
            for (int ct = 0; ct < 4; ct++)
                #pragma unroll
                for (int j = 0; j < 4; j++) s += __expf(v[ct][j] - m1);
            #pragma unroll
            for (int off = 16; off < 64; off <<= 1) s += __shfl_xor(s, off);
        }
        if (lq == 0) {
            int vr = vr0 + waveY * 64 + rt * 16 + lm;
            float4 st = make_float4(m1, m2, __int_as_float(k1), s);
            part4[(size_t)vr * 8 + codeblk * 2 + waveX] = st;
        }
    }
}

// ---- combine the 8 per-slice partials of each row; write idx/prob; flag rescues
__global__ void combine_rows(const float* __restrict__ partials,
                             int* __restrict__ idx1, int* __restrict__ idx2,
                             float* __restrict__ prob,
                             int* __restrict__ rlist, int* __restrict__ cnt) {
    int vr = blockIdx.x * 256 + threadIdx.x;      // grid 296*256 = 75776 exact
    const float4* p = (const float4*)partials + (size_t)vr * 8;
    float sm[8], ss[8];
    float4 a = p[0];
    float m1 = a.x, m2 = a.y; int k1 = __float_as_int(a.z);
    sm[0] = a.x; ss[0] = a.w;
    #pragma unroll
    for (int j = 1; j < 8; j++) {
        float4 b = p[j];
        sm[j] = b.x; ss[j] = b.w;
        int kk = __float_as_int(b.z);
        if (b.x > m1 || (b.x == m1 && kk < k1)) { m2 = fmaxf(m1, b.y); m1 = b.x; k1 = kk; }
        else m2 = fmaxf(m2, b.x);
    }
    float S = 0.f;
    #pragma unroll
    for (int j = 0; j < 8; j++) S += ss[j] * __expf(sm[j] - m1);
    if (vr < 43008) { idx1[vr] = k1; prob[vr] = 1.0f / S; }
    else idx2[vr - 43008] = k1;
    if (m1 - m2 < EPS_V) { int pos = atomicAdd(cnt, 1); rlist[pos] = vr; }
}

// ---- exact fp64 recompute for flagged rows (idx + prob)
__launch_bounds__(256)
__global__ void rescue_exact(const float* __restrict__ out0,
                             const float* __restrict__ feat12,
                             const float* __restrict__ codebooks,
                             const double* __restrict__ cnd,
                             const int* __restrict__ rlist, const int* __restrict__ cnt,
                             int* __restrict__ idx1, int* __restrict__ idx2,
                             float* __restrict__ prob) {
    __shared__ double sfd[256];
    __shared__ double rv[4]; __shared__ int rk[4]; __shared__ double rs[4];
    __shared__ double gvmax; __shared__ int gkmax;
    int tid = threadIdx.x;
    int lane = tid & 63, wave = tid >> 6;
    int n = cnt[0];
    for (int e = blockIdx.x; e < n; e += gridDim.x) {
        int vr = rlist[e];
        int book = vr >= 43008;
        int fr = book ? vr - 43008 : vr;
        sfd[tid] = (double)feat_elem(out0, feat12, fr, tid);
        __syncthreads();
        const float* cb = codebooks + (size_t)book * 131072;
        double vloc[2]; int kk[2];
        #pragma unroll
        for (int h = 0; h < 2; h++) {
            int k = h * 256 + tid;
            const float* cp = cb + (size_t)k * 256;
            double d0 = 0.0, d1 = 0.0, d2 = 0.0, d3 = 0.0;
            for (int c = 0; c < 256; c += 4) {
                float4 cv = *(const float4*)&cp[c];
                d0 = fma((double)cv.x, sfd[c],     d0);
                d1 = fma((double)cv.y, sfd[c + 1], d1);
                d2 = fma((double)cv.z, sfd[c + 2], d2);
                d3 = fma((double)cv.w, sfd[c + 3], d3);
            }
            double dot = (d0 + d1) + (d2 + d3);
            vloc[h] = 2.0 * dot - cnd[book * 512 + k];
            kk[h] = k;
        }
        double bv = vloc[0]; int bk = kk[0];
        if (vloc[1] > bv || (vloc[1] == bv && kk[1] < bk)) { bv = vloc[1]; bk = kk[1]; }
        #pragma unroll
        for (int off = 32; off; off >>= 1) {
            double vo = __shfl_xor(bv, off);
            int ko = __shfl_xor(bk, off);
            if (vo > bv || (vo == bv && ko < bk)) { bv = vo; bk = ko; }
        }
        if (lane == 0) { rv[wave] = bv; rk[wave] = bk; }
        __syncthreads();
        if (tid == 0) {
            double v0 = rv[0]; int K = rk[0];
            #pragma unroll
            for (int w = 1; w < 4; w++)
                if (rv[w] > v0 || (rv[w] == v0 && rk[w] < K)) { v0 = rv[w]; K = rk[w]; }
            gvmax = v0; gkmax = K;
        }
        __syncthreads();
        double vm = gvmax;
        double s = exp(vloc[0] - vm) + exp(vloc[1] - vm);
        #pragma unroll
        for (int off = 32; off; off >>= 1) s += __shfl_xor(s, off);
        if (lane == 0) rs[wave] = s;
        __syncthreads();
        if (tid == 0) {
            double S = ((rs[0] + rs[1]) + rs[2]) + rs[3];
            if (book) idx2[fr] = gkmax;
            else { idx1[vr] = gkmax; prob[vr] = (float)(1.0 / S); }
        }
        __syncthreads();
    }
}

// ---- fuse stage 1: decide per pixel; defer prob-fragile pixels to fuse2.
//      outS = (q1+q2)/2 (== ste0 to 1 ulp); out0 already written by encode.
//      2 channel-half blocks per (b,y); outZ/dlist writes gated to half 0.
__launch_bounds__(256)
__global__ void fuse1(const float* __restrict__ prob,
                      const int* __restrict__ idx1, const int* __restrict__ idx2,
                      const float* __restrict__ codebooks,
                      float* __restrict__ outZ, float* __restrict__ outS,
                      int* __restrict__ dlist, int* __restrict__ cnt) {
    __shared__ int i1_s[64], i2_s[64], defer_s[64];
    int tid = threadIdx.x;
    int bid = blockIdx.x;
    int chh = bid & 1;                       // channel half
    int rowid = bid >> 1;
    int b = rowid >> 6, y = rowid & 63;

    if (tid < 64) {
        int x = tid;
        int r0 = (b * 64 + y) * 64 + x;
        int r1 = 32768 + (b * 32 + (y >> 1)) * 32 + (x >> 1);
        int r2 = 40960 + (b * 16 + (y >> 2)) * 16 + (x >> 2);
        float p0 = prob[r0], p1 = prob[r1], p2 = prob[r2];
        int rsel = r0; float best = p0;          // strict > keeps first-max
        if (p1 > best) { best = p1; rsel = r1; }
        if (p2 > best) { best = p2; rsel = r2; }
        float second = (rsel == r0) ? fmaxf(p1, p2)
                     : (rsel == r1) ? fmaxf(p0, p2) : fmaxf(p0, p1);
        int defer = (best - second < EPS_P_REL * best) ? 1 : 0;
        defer_s[x] = defer;
        if (defer) {
            if (chh == 0) {                  // half 0 owns list append + outZ
                int pos = atomicAdd(cnt + 1, 1);
                dlist[pos] = (b << 12) | (y << 6) | x;
            }
            i1_s[x] = 0; i2_s[x] = 0;        // unused
        } else {
            int i1 = idx1[rsel], i2 = idx2[r0];
            i1_s[x] = i1; i2_s[x] = i2;
            if (chh == 0) {
                size_t zb = (size_t)b * 8192 + (size_t)y * 64 + x;
                outZ[zb] = (float)i1;
                outZ[zb + 4096] = (float)i2;
            }
        }
    }
    __syncthreads();

    int x = tid & 63, cc = tid >> 6;
    const float* q1p = codebooks + (size_t)i1_s[x] * 256;
    const float* q2p = codebooks + (size_t)(512 + i2_s[x]) * 256;
    if (defer_s[x]) return;                  // fuse2 writes deferred pixels
    #pragma unroll
    for (int it = 0; it < 8; it++) {
        int c = chh * 128 + it * 16 + cc * 4;
        float4 q1 = *(const float4*)&q1p[c];
        float4 q2 = *(const float4*)&q2p[c];
        size_t o = (((size_t)b * 256 + c) * 64 + y) * 64 + x;
        outS[o]         = (q1.x + q2.x) * 0.5f;
        outS[o + 4096]  = (q1.y + q2.y) * 0.5f;
        outS[o + 8192]  = (q1.z + q2.z) * 0.5f;
        outS[o + 12288] = (q1.w + q2.w) * 0.5f;
    }
}

// ---- fuse stage 2: deferred pixels, full fp64 (3 rows x 512 codes each)
__launch_bounds__(256)
__global__ void fuse2(const float* __restrict__ out0,
                      const float* __restrict__ feat12,
                      const float* __restrict__ codebooks,
                      const double* __restrict__ cnd,
                      const int* __restrict__ idx2,
                      const int* __restrict__ dlist, const int* __restrict__ cnt,
                      float* __restrict__ outZ, float* __restrict__ outS) {
    __shared__ double sfd[256];
    __shared__ double rv[4]; __shared__ int rk[4]; __shared__ double rs[4];
    __shared__ double gvmax;
    __shared__ double pRes[3]; __shared__ int kRes[3];
    __shared__ int selS, i2S;
    int tid = threadIdx.x;
    int lane = tid & 63, wave = tid >> 6;
    int n = cnt[1];
    for (int e = blockIdx.x; e < n; e += gridDim.x) {
        int px = dlist[e];
        int b = px >> 12, y = (px >> 6) & 63, x = px & 63;
        int r0 = (b * 64 + y) * 64 + x;
        int r1 = 32768 + (b * 32 + (y >> 1)) * 32 + (x >> 1);
        int r2 = 40960 + (b * 16 + (y >> 2)) * 16 + (x >> 2);
        int rows[3] = {r0, r1, r2};
        for (int s3 = 0; s3 < 3; s3++) {
            sfd[tid] = (double)feat_elem(out0, feat12, rows[s3], tid);
            __syncthreads();
            double vloc[2];
            #pragma unroll
            for (int h = 0; h < 2; h++) {
                int k = h * 256 + tid;
                const float* cp = codebooks + (size_t)k * 256;
                double d0 = 0.0, d1 = 0.0, d2 = 0.0, d3 = 0.0;
                for (int c = 0; c < 256; c += 4) {
                    float4 cv = *(const float4*)&cp[c];
                    d0 = fma((double)cv.x, sfd[c],     d0);
                    d1 = fma((double)cv.y, sfd[c + 1], d1);
                    d2 = fma((double)cv.z, sfd[c + 2], d2);
                    d3 = fma((double)cv.w, sfd[c + 3], d3);
                }
                double dot = (d0 + d1) + (d2 + d3);
                vloc[h] = 2.0 * dot - cnd[k];
            }
            double bv = vloc[0]; int bk = tid;
            if (vloc[1] > bv) { bv = vloc[1]; bk = tid + 256; }
            #pragma unroll
            for (int off = 32; off; off >>= 1) {
                double vo = __shfl_xor(bv, off);
                int ko = __shfl_xor(bk, off);
                if (vo > bv || (vo == bv && ko < bk)) { bv = vo; bk = ko; }
            }
            if (lane == 0) { rv[wave] = bv; rk[wave] = bk; }
            __syncthreads();
            if (tid == 0) {
                double v0 = rv[0]; int K = rk[0];
                #pragma unroll
                for (int w = 1; w < 4; w++)
                    if (rv[w] > v0 || (rv[w] == v0 && rk[w] < K)) { v0 = rv[w]; K = rk[w]; }
                gvmax = v0; kRes[s3] = K;
            }
            __syncthreads();
            double vm = gvmax;
            double s = exp(vloc[0] - vm) + exp(vloc[1] - vm);
            #pragma unroll
            for (int off = 32; off; off >>= 1) s += __shfl_xor(s, off);
            if (lane == 0) rs[wave] = s;
            __syncthreads();
            if (tid == 0) pRes[s3] = 1.0 / (((rs[0] + rs[1]) + rs[2]) + rs[3]);
            __syncthreads();
        }
        if (tid == 0) {
            int sel = 0; double best = pRes[0];
            if (pRes[1] > best) { best = pRes[1]; sel = 1; }
            if (pRes[2] > best) { best = pRes[2]; sel = 2; }
            selS = sel;
            int i2 = idx2[r0];
            i2S = i2;
            size_t zb = (size_t)b * 8192 + (size_t)y * 64 + x;
            outZ[zb] = (float)kRes[sel];
            outZ[zb + 4096] = (float)i2;
        }
        __syncthreads();
        int sel = selS;
        int c = tid;
        float q1 = codebooks[(size_t)kRes[sel] * 256 + c];
        float q2 = codebooks[(size_t)(512 + i2S) * 256 + c];
        size_t o = (((size_t)b * 256 + c) * 64 + y) * 64 + x;
        outS[o] = (q1 + q2) * 0.5f;          // == e_f + (q_f - e_f) to 1 ulp
        __syncthreads();
    }
}

extern "C" void kernel_launch(void* const* d_in, const int* in_sizes, int n_in,
                              void* d_out, int out_size, void* d_ws, size_t ws_size,
                              hipStream_t stream) {
    (void)in_sizes; (void)n_in; (void)out_size; (void)ws_size;
    const float* image     = (const float*)d_in[0];   // [8,3,256,256]
    const float* conv_w    = (const float*)d_in[1];   // [256,3,4,4]
    const float* conv_b    = (const float*)d_in[2];   // [256]
    const float* codebooks = (const float*)d_in[3];   // [4,512,256]

    float*  ws     = (float*)d_ws;
    float*  feat12 = ws + FEAT12_OFF;
    unsigned short* fbl = (unsigned short*)(ws + FBLO_OFF);
    float*  parts  = ws + PART_OFF;
    float*  prob   = ws + PROB_OFF;
    int*    idx1   = (int*)(ws + IDX1_OFF);
    int*    idx2   = (int*)(ws + IDX2_OFF);
    float*  cnf    = ws + CNF_OFF;
    double* cnd    = (double*)(ws + CND_OFF);
    unsigned short* cbs = (unsigned short*)(ws + CBS_OFF);
    float*  img1   = ws + IMG1_OFF;
    float*  img2   = ws + IMG2_OFF;
    int*    rlist  = (int*)(ws + RLIST_OFF);
    int*    dlist  = (int*)(ws + DLIST_OFF);
    int*    cnt    = (int*)(ws + CNT_OFF);

    float* out  = (float*)d_out;
    float* out0 = out;                       // written by encode (final)
    float* outZ = out + 8388608;
    float* outS = out + 8454144;
    // featbf hi plane lives in the outS region until fuse1/fuse2 rewrite it.
    unsigned short* fbh = (unsigned short*)outS;

    prep<<<3200, 256, 0, stream>>>(image, codebooks, img1, img2, cnd, cnf, cbs, cnt);
    encode_all<<<1408, 256, 0, stream>>>(image, img1, img2, conv_w, conv_b,
                                         feat12, fbh, fbl, out0);
    match_bulk<<<2368, 256, 0, stream>>>(fbh, fbl, cbs, cnf, parts);
    combine_rows<<<296, 256, 0, stream>>>(parts, idx1, idx2, prob, rlist, cnt);
    rescue_exact<<<1024, 256, 0, stream>>>(out0, feat12, codebooks, cnd, rlist, cnt,
                                           idx1, idx2, prob);
    fuse1<<<1024, 256, 0, stream>>>(prob, idx1, idx2, codebooks, outZ, outS, dlist, cnt);
    fuse2<<<512, 256, 0, stream>>>(out0, feat12, codebooks, cnd, idx2, dlist, cnt,
                                   outZ, outS);
}